// Round 1
// baseline (81.010 us; speedup 1.0000x reference)
//
#include <hip/hip_runtime.h>
#include <math.h>

#define Bq 512
#define Nq 128
#define Mq 256
#define Eq 64
#define SM1 1023           // S-1 distance rows (s = 0..1022)
#define LOG2E 1.4426950408889634f

// Wave64 sum-reduce via DPP (no DS traffic); returns total, uniform across lanes.
__device__ __forceinline__ float waveReduceSumAll(float x) {
    x += __int_as_float(__builtin_amdgcn_update_dpp(0, __float_as_int(x), 0x111, 0xf, 0xf, true)); // row_shr:1
    x += __int_as_float(__builtin_amdgcn_update_dpp(0, __float_as_int(x), 0x112, 0xf, 0xf, true)); // row_shr:2
    x += __int_as_float(__builtin_amdgcn_update_dpp(0, __float_as_int(x), 0x114, 0xf, 0xf, true)); // row_shr:4
    x += __int_as_float(__builtin_amdgcn_update_dpp(0, __float_as_int(x), 0x118, 0xf, 0xf, true)); // row_shr:8
    x += __int_as_float(__builtin_amdgcn_update_dpp(0, __float_as_int(x), 0x142, 0xf, 0xf, true)); // row_bcast:15
    x += __int_as_float(__builtin_amdgcn_update_dpp(0, __float_as_int(x), 0x143, 0xf, 0xf, true)); // row_bcast:31
    return __int_as_float(__builtin_amdgcn_readlane(__float_as_int(x), 63));
}

extern "C" __global__ void __launch_bounds__(512, 4)
gating_kernel(const float* __restrict__ context,
              const float* __restrict__ z,
              const float* __restrict__ noise,
              const float* __restrict__ conv_w,
              const float* __restrict__ conv_b,
              const float* __restrict__ D,
              const float* __restrict__ sigma,
              const float* __restrict__ temp1,
              const float* __restrict__ W1,
              const float* __restrict__ b1,
              const float* __restrict__ W2,
              const float* __restrict__ b2,
              const float* __restrict__ temp2,
              float* __restrict__ out)
{
    const int b    = blockIdx.x;
    const int tid  = threadIdx.x;
    const int wave = tid >> 6;
    const int lane = tid & 63;

    __shared__ __align__(16) float sA0[8][128];
    __shared__ __align__(16) float sA1[8][128];
    __shared__ float smx[8];
    __shared__ float sZ[8];
    __shared__ __align__(16) float gA0[128];
    __shared__ __align__(16) float gA1[128];
    __shared__ __align__(16) float semb[128];
    __shared__ __align__(16) float szc[128];
    __shared__ __align__(16) float szcol[256];
    __shared__ __align__(16) float shb[64];

    // ---- phase 0: stage z column; z_current = D @ z + sigma * noise ----
    if (tid < 256) szcol[tid] = z[tid * Bq + b];
    __syncthreads();
    if (tid < 128) {
        const float4* Drow = (const float4*)(D + tid * Mq);
        float acc0 = 0.f, acc1 = 0.f, acc2 = 0.f, acc3 = 0.f;
        #pragma unroll 8
        for (int i = 0; i < 64; ++i) {
            float4 dv = Drow[i];
            acc0 = fmaf(dv.x, szcol[4 * i + 0], acc0);
            acc1 = fmaf(dv.y, szcol[4 * i + 1], acc1);
            acc2 = fmaf(dv.z, szcol[4 * i + 2], acc2);
            acc3 = fmaf(dv.w, szcol[4 * i + 3], acc3);
        }
        szc[tid] = (acc0 + acc1) + (acc2 + acc3) + sigma[tid] * noise[tid * Bq + b];
    }
    __syncthreads();

    const float invt = LOG2E / fabsf(temp1[0]);
    const float zcx = szc[2 * lane];
    const float zcy = szc[2 * lane + 1];

    // ---- phase 1: streaming online-softmax weighted sums over s-chunk ----
    const int lo = wave * 128;
    const int hi = min(SM1, lo + 128);          // distance rows owned: [lo, hi)
    const size_t rowstride = (size_t)Bq * Nq;   // 65536 floats per s-step
    const float* p = context + (size_t)b * Nq + 2 * lane;

    float mrun = -INFINITY, Zrun = 0.f, wprev = 0.f;
    float a0x = 0.f, a0y = 0.f, a1x = 0.f, a1y = 0.f;

    float2 cb0 = *(const float2*)(p + (size_t)lo * rowstride);
    float2 cb1 = *(const float2*)(p + (size_t)(lo + 1) * rowstride);

    for (int r = lo; r <= hi; ++r) {
        float2 c = cb0;
        cb0 = cb1;
        if (r + 2 <= hi)
            cb1 = *(const float2*)(p + (size_t)(r + 2) * rowstride);
        if (r > lo) {                       // A1 += w[r-1] * context[r]
            a1x = fmaf(wprev, c.x, a1x);
            a1y = fmaf(wprev, c.y, a1y);
        }
        if (r < hi) {                       // distance row r, weight w[r]
            float d = fabsf(c.x - zcx) + fabsf(c.y - zcy);
            d = waveReduceSumAll(d);        // uniform across lanes
            float v = -d * invt;            // log2-domain
            float w;
            if (v > mrun) {
                float sc = exp2f(mrun - v); // first iter: exp2(-inf)=0 zeroes empties
                Zrun *= sc; a0x *= sc; a0y *= sc; a1x *= sc; a1y *= sc; wprev *= sc;
                mrun = v; w = 1.f;
            } else {
                w = exp2f(v - mrun);
            }
            Zrun += w;
            a0x = fmaf(w, c.x, a0x);
            a0y = fmaf(w, c.y, a0y);
            wprev = w;
        }
    }

    *(float2*)&sA0[wave][2 * lane] = make_float2(a0x, a0y);
    *(float2*)&sA1[wave][2 * lane] = make_float2(a1x, a1y);
    if (lane == 0) { smx[wave] = mrun; sZ[wave] = Zrun; }
    __syncthreads();

    // ---- phase 2: merge 8 partial online-softmax states ----
    float gm = smx[0];
    #pragma unroll
    for (int k = 1; k < 8; ++k) gm = fmaxf(gm, smx[k]);
    float scl[8];
    float Gz = 0.f;
    #pragma unroll
    for (int k = 0; k < 8; ++k) { scl[k] = exp2f(smx[k] - gm); Gz = fmaf(scl[k], sZ[k], Gz); }

    if (tid < 128) {
        float acc = 0.f;
        #pragma unroll
        for (int k = 0; k < 8; ++k) acc = fmaf(scl[k], sA0[k][tid], acc);
        gA0[tid] = acc;
    } else if (tid < 256) {
        const int t = tid - 128;
        float acc = 0.f;
        #pragma unroll
        for (int k = 0; k < 8; ++k) acc = fmaf(scl[k], sA1[k][t], acc);
        gA1[t] = acc;
    }
    __syncthreads();

    // ---- phase 3: embedding[o] = (w0[o,:]·A0 + w1[o,:]·A1)/Z + conv_b[o] ----
    if (tid < 128) {
        const float4* wr = (const float4*)(conv_w + tid * 256);  // [o][i][k] pairs
        float acc = 0.f;
        #pragma unroll 8
        for (int i = 0; i < 64; ++i) {
            float4 w4 = wr[i];   // w0[o,2i], w1[o,2i], w0[o,2i+1], w1[o,2i+1]
            acc = fmaf(w4.x, gA0[2 * i], acc);
            acc = fmaf(w4.y, gA1[2 * i], acc);
            acc = fmaf(w4.z, gA0[2 * i + 1], acc);
            acc = fmaf(w4.w, gA1[2 * i + 1], acc);
        }
        semb[tid] = acc / Gz + conv_b[tid];
    }
    __syncthreads();

    // ---- phase 4: MLP layer 1, h = relu(W1 @ [emb; z] + b1) ----
    if (tid < 64) {
        const float* w1r = W1 + tid * (Nq + Mq);
        float acc = b1[tid];
        #pragma unroll 8
        for (int i = 0; i < 128; ++i) acc = fmaf(w1r[i], semb[i], acc);
        #pragma unroll 8
        for (int i = 0; i < 256; ++i) acc = fmaf(w1r[128 + i], szcol[i], acc);
        shb[tid] = fmaxf(acc, 0.f);
    }
    __syncthreads();

    // ---- phase 5: MLP layer 2 + softmax over E (wave 0 only) ----
    if (tid < 64) {
        const float* w2r = W2 + tid * Eq;
        float acc = b2[tid];
        #pragma unroll 8
        for (int j = 0; j < 64; ++j) acc = fmaf(w2r[j], shb[j], acc);
        float v = -acc * (LOG2E / fabsf(temp2[0]));
        float mx = v;
        #pragma unroll
        for (int off = 32; off > 0; off >>= 1) mx = fmaxf(mx, __shfl_xor(mx, off, 64));
        float w = exp2f(v - mx);
        float s = w;
        #pragma unroll
        for (int off = 32; off > 0; off >>= 1) s += __shfl_xor(s, off, 64);
        out[tid * Bq + b] = w / s;
    }
}

extern "C" void kernel_launch(void* const* d_in, const int* in_sizes, int n_in,
                              void* d_out, int out_size, void* d_ws, size_t ws_size,
                              hipStream_t stream) {
    const float* context = (const float*)d_in[0];
    const float* z       = (const float*)d_in[1];
    const float* noise   = (const float*)d_in[2];
    const float* conv_w  = (const float*)d_in[3];
    const float* conv_b  = (const float*)d_in[4];
    const float* D       = (const float*)d_in[5];
    const float* sigma   = (const float*)d_in[6];
    const float* temp1   = (const float*)d_in[7];
    const float* W1      = (const float*)d_in[8];
    const float* b1      = (const float*)d_in[9];
    const float* W2      = (const float*)d_in[10];
    const float* b2      = (const float*)d_in[11];
    const float* temp2   = (const float*)d_in[12];
    float* out = (float*)d_out;

    gating_kernel<<<dim3(Bq), dim3(512), 0, stream>>>(
        context, z, noise, conv_w, conv_b, D, sigma, temp1,
        W1, b1, W2, b2, temp2, out);
}

// Round 2
// 69.869 us; speedup vs baseline: 1.1595x; 1.1595x over previous
//
#include <hip/hip_runtime.h>
#include <math.h>

#define Bq 512
#define Nq 128
#define Mq 256
#define Eq 64
#define SM1 1023           // S-1 distance rows (s = 0..1022)
#define LOG2E 1.4426950408889634f

// Wave64 sum-reduce via DPP (no DS traffic); returns total, uniform across lanes.
__device__ __forceinline__ float waveReduceSumAll(float x) {
    x += __int_as_float(__builtin_amdgcn_update_dpp(0, __float_as_int(x), 0x111, 0xf, 0xf, true)); // row_shr:1
    x += __int_as_float(__builtin_amdgcn_update_dpp(0, __float_as_int(x), 0x112, 0xf, 0xf, true)); // row_shr:2
    x += __int_as_float(__builtin_amdgcn_update_dpp(0, __float_as_int(x), 0x114, 0xf, 0xf, true)); // row_shr:4
    x += __int_as_float(__builtin_amdgcn_update_dpp(0, __float_as_int(x), 0x118, 0xf, 0xf, true)); // row_shr:8
    x += __int_as_float(__builtin_amdgcn_update_dpp(0, __float_as_int(x), 0x142, 0xf, 0xf, true)); // row_bcast:15
    x += __int_as_float(__builtin_amdgcn_update_dpp(0, __float_as_int(x), 0x143, 0xf, 0xf, true)); // row_bcast:31
    return __int_as_float(__builtin_amdgcn_readlane(__float_as_int(x), 63));
}

// One distance row: slot K of the ring, absolute row RK. Branchless online softmax.
// c = context[RK], cn = context[RK+1] (already in ring). Optionally refill slot K
// with row min(RK+8, hi) (clamped -> no OOB, redundant tail loads are harmless).
#define ROW_BODY(K, RK, DOLOAD)                                          \
    {                                                                    \
        float2 c  = buf[(K)];                                            \
        float2 cn = buf[((K) + 1) & 7];                                  \
        if (DOLOAD) buf[(K)] = p2[(size_t)min((RK) + 8, hi) * 32768];    \
        float d = fabsf(c.x - zcx) + fabsf(c.y - zcy);                   \
        d = waveReduceSumAll(d);                                         \
        float v = d * negt;            /* log2 domain, negated */        \
        float mnew = fmaxf(mrun, v);                                     \
        float sc = exp2f(mrun - mnew); /* ==1 on common path */          \
        float w  = exp2f(v - mnew);                                      \
        mrun = mnew;                                                     \
        Zrun = fmaf(Zrun, sc, w);                                        \
        a0x = fmaf(a0x, sc, w * c.x);                                    \
        a0y = fmaf(a0y, sc, w * c.y);                                    \
        a1x = fmaf(a1x, sc, w * cn.x);                                   \
        a1y = fmaf(a1y, sc, w * cn.y);                                   \
    }

extern "C" __global__ void __launch_bounds__(512, 4)
gating_kernel(const float* __restrict__ context,
              const float* __restrict__ z,
              const float* __restrict__ noise,
              const float* __restrict__ conv_w,
              const float* __restrict__ conv_b,
              const float* __restrict__ D,
              const float* __restrict__ sigma,
              const float* __restrict__ temp1,
              const float* __restrict__ W1,
              const float* __restrict__ b1,
              const float* __restrict__ W2,
              const float* __restrict__ b2,
              const float* __restrict__ temp2,
              float* __restrict__ out)
{
    const int b    = blockIdx.x;
    const int tid  = threadIdx.x;
    const int wave = tid >> 6;
    const int lane = tid & 63;

    __shared__ __align__(16) float sA0[8][128];
    __shared__ __align__(16) float sA1[8][128];
    __shared__ float smx[8];
    __shared__ float sZ[8];
    __shared__ __align__(16) float gA0[128];
    __shared__ __align__(16) float gA1[128];
    __shared__ __align__(16) float semb[128];
    __shared__ __align__(16) float szc[128];
    __shared__ __align__(16) float szcol[256];
    __shared__ __align__(16) float shb[64];

    // ---- ring preload: issue the first 8 row loads BEFORE the prologue ----
    const int lo = wave * 128;
    const int hi = min(SM1, lo + 128);          // distance rows owned: [lo, hi)
    const float2* p2 = (const float2*)context + (size_t)b * 64 + lane;  // row stride 32768 float2

    float2 buf[8];
    #pragma unroll
    for (int j = 0; j < 8; ++j)
        buf[j] = p2[(size_t)min(lo + j, hi) * 32768];

    // ---- phase 0: stage z column; z_current = D @ z + sigma * noise ----
    if (tid < 256) szcol[tid] = z[tid * Bq + b];
    __syncthreads();
    if (tid < 128) {
        const float4* Drow = (const float4*)(D + tid * Mq);
        float acc0 = 0.f, acc1 = 0.f, acc2 = 0.f, acc3 = 0.f;
        #pragma unroll 8
        for (int i = 0; i < 64; ++i) {
            float4 dv = Drow[i];
            acc0 = fmaf(dv.x, szcol[4 * i + 0], acc0);
            acc1 = fmaf(dv.y, szcol[4 * i + 1], acc1);
            acc2 = fmaf(dv.z, szcol[4 * i + 2], acc2);
            acc3 = fmaf(dv.w, szcol[4 * i + 3], acc3);
        }
        szc[tid] = (acc0 + acc1) + (acc2 + acc3) + sigma[tid] * noise[tid * Bq + b];
    }
    __syncthreads();

    const float negt = -LOG2E / fabsf(temp1[0]);
    const float zcx = szc[2 * lane];
    const float zcy = szc[2 * lane + 1];

    // ---- phase 1: streaming online-softmax weighted sums, 8-deep pipeline ----
    float mrun = -INFINITY, Zrun = 0.f;
    float a0x = 0.f, a0y = 0.f, a1x = 0.f, a1y = 0.f;

    int r = lo;
    for (; r + 8 <= hi; r += 8) {
        #pragma unroll
        for (int k = 0; k < 8; ++k)
            ROW_BODY(k, r + k, 1)
    }
    // tail: <=7 rows, data already resident in ring slots 0..7
    #pragma unroll
    for (int j = 0; j < 7; ++j) {
        if (r + j < hi)
            ROW_BODY(j, r + j, 0)
    }

    *(float2*)&sA0[wave][2 * lane] = make_float2(a0x, a0y);
    *(float2*)&sA1[wave][2 * lane] = make_float2(a1x, a1y);
    if (lane == 0) { smx[wave] = mrun; sZ[wave] = Zrun; }
    __syncthreads();

    // ---- phase 2: merge 8 partial online-softmax states ----
    float gm = smx[0];
    #pragma unroll
    for (int k = 1; k < 8; ++k) gm = fmaxf(gm, smx[k]);
    float scl[8];
    float Gz = 0.f;
    #pragma unroll
    for (int k = 0; k < 8; ++k) { scl[k] = exp2f(smx[k] - gm); Gz = fmaf(scl[k], sZ[k], Gz); }

    if (tid < 128) {
        float acc = 0.f;
        #pragma unroll
        for (int k = 0; k < 8; ++k) acc = fmaf(scl[k], sA0[k][tid], acc);
        gA0[tid] = acc;
    } else if (tid < 256) {
        const int t = tid - 128;
        float acc = 0.f;
        #pragma unroll
        for (int k = 0; k < 8; ++k) acc = fmaf(scl[k], sA1[k][t], acc);
        gA1[t] = acc;
    }
    __syncthreads();

    // ---- phase 3: embedding[o] = (w0[o,:]·A0 + w1[o,:]·A1)/Z + conv_b[o] ----
    if (tid < 128) {
        const float4* wr = (const float4*)(conv_w + tid * 256);  // [o][i][k] pairs
        float acc = 0.f;
        #pragma unroll 8
        for (int i = 0; i < 64; ++i) {
            float4 w4 = wr[i];   // w0[o,2i], w1[o,2i], w0[o,2i+1], w1[o,2i+1]
            acc = fmaf(w4.x, gA0[2 * i], acc);
            acc = fmaf(w4.y, gA1[2 * i], acc);
            acc = fmaf(w4.z, gA0[2 * i + 1], acc);
            acc = fmaf(w4.w, gA1[2 * i + 1], acc);
        }
        semb[tid] = acc / Gz + conv_b[tid];
    }
    __syncthreads();

    // ---- phase 4: MLP layer 1, h = relu(W1 @ [emb; z] + b1) ----
    if (tid < 64) {
        const float* w1r = W1 + tid * (Nq + Mq);
        float acc = b1[tid];
        #pragma unroll 8
        for (int i = 0; i < 128; ++i) acc = fmaf(w1r[i], semb[i], acc);
        #pragma unroll 8
        for (int i = 0; i < 256; ++i) acc = fmaf(w1r[128 + i], szcol[i], acc);
        shb[tid] = fmaxf(acc, 0.f);
    }
    __syncthreads();

    // ---- phase 5: MLP layer 2 + softmax over E (wave 0 only) ----
    if (tid < 64) {
        const float* w2r = W2 + tid * Eq;
        float acc = b2[tid];
        #pragma unroll 8
        for (int j = 0; j < 64; ++j) acc = fmaf(w2r[j], shb[j], acc);
        float v = -acc * (LOG2E / fabsf(temp2[0]));
        float mx = v;
        #pragma unroll
        for (int off = 32; off > 0; off >>= 1) mx = fmaxf(mx, __shfl_xor(mx, off, 64));
        float w = exp2f(v - mx);
        float s = w;
        #pragma unroll
        for (int off = 32; off > 0; off >>= 1) s += __shfl_xor(s, off, 64);
        out[tid * Bq + b] = w / s;
    }
}

extern "C" void kernel_launch(void* const* d_in, const int* in_sizes, int n_in,
                              void* d_out, int out_size, void* d_ws, size_t ws_size,
                              hipStream_t stream) {
    const float* context = (const float*)d_in[0];
    const float* z       = (const float*)d_in[1];
    const float* noise   = (const float*)d_in[2];
    const float* conv_w  = (const float*)d_in[3];
    const float* conv_b  = (const float*)d_in[4];
    const float* D       = (const float*)d_in[5];
    const float* sigma   = (const float*)d_in[6];
    const float* temp1   = (const float*)d_in[7];
    const float* W1      = (const float*)d_in[8];
    const float* b1      = (const float*)d_in[9];
    const float* W2      = (const float*)d_in[10];
    const float* b2      = (const float*)d_in[11];
    const float* temp2   = (const float*)d_in[12];
    float* out = (float*)d_out;

    gating_kernel<<<dim3(Bq), dim3(512), 0, stream>>>(
        context, z, noise, conv_w, conv_b, D, sigma, temp1,
        W1, b1, W2, b2, temp2, out);
}